// Round 1
// baseline (9372.646 us; speedup 1.0000x reference)
//
#include <hip/hip_runtime.h>
#include <math.h>

#define EPSBN 1e-5f

__device__ __forceinline__ float elu1(float x) { return x > 0.f ? x : expm1f(x); }

// ---------- Stage 1 (slab path): s[k*N + out_idx[k,m]] += x[in_idx[k,m]] ----------
__global__ void s1_scatter_slab(const float* __restrict__ x,
                                const int* __restrict__ in_idx,
                                const int* __restrict__ out_idx,
                                float* __restrict__ s, int M, int N) {
    int m = blockIdx.x * blockDim.x + threadIdx.x;
    if (m >= M) return;
    int k = blockIdx.y;
    size_t e = (size_t)k * M + m;
    float xv = x[in_idx[e]];
    unsafeAtomicAdd(&s[(size_t)k * N + out_idx[e]], xv);
}

// Combine slabs with W1, fuse BN1+ELU, write h [N,16]
__global__ void s1_combine(const float* __restrict__ s,
                           const float* __restrict__ W1,
                           const float* __restrict__ g1, const float* __restrict__ b1,
                           const float* __restrict__ m1, const float* __restrict__ v1,
                           float* __restrict__ h, int N, int K) {
    __shared__ float w[32 * 16];
    __shared__ float sc[16], bi[16];
    for (int t = threadIdx.x; t < K * 16; t += blockDim.x) w[t] = W1[t];
    if (threadIdx.x < 16) {
        float scale = g1[threadIdx.x] * rsqrtf(v1[threadIdx.x] + EPSBN);
        sc[threadIdx.x] = scale;
        bi[threadIdx.x] = b1[threadIdx.x] - m1[threadIdx.x] * scale;
    }
    __syncthreads();
    int n = blockIdx.x * blockDim.x + threadIdx.x;
    if (n >= N) return;
    float acc[16];
#pragma unroll
    for (int c = 0; c < 16; ++c) acc[c] = 0.f;
    for (int k = 0; k < K; ++k) {
        float sv = s[(size_t)k * N + n];
#pragma unroll
        for (int c = 0; c < 16; ++c) acc[c] = fmaf(sv, w[k * 16 + c], acc[c]);
    }
    float4 o[4];
#pragma unroll
    for (int q = 0; q < 4; ++q) {
        o[q].x = elu1(acc[q * 4 + 0] * sc[q * 4 + 0] + bi[q * 4 + 0]);
        o[q].y = elu1(acc[q * 4 + 1] * sc[q * 4 + 1] + bi[q * 4 + 1]);
        o[q].z = elu1(acc[q * 4 + 2] * sc[q * 4 + 2] + bi[q * 4 + 2]);
        o[q].w = elu1(acc[q * 4 + 3] * sc[q * 4 + 3] + bi[q * 4 + 3]);
    }
    float4* hv = (float4*)(h + (size_t)n * 16);
#pragma unroll
    for (int q = 0; q < 4; ++q) hv[q] = o[q];
}

// ---------- Stage 1 fallback (small ws): direct 16-channel atomic scatter ----------
__global__ void s1_scatter_direct(const float* __restrict__ x,
                                  const float* __restrict__ W1,
                                  const int* __restrict__ in_idx,
                                  const int* __restrict__ out_idx,
                                  float* __restrict__ hacc, int M) {
    int k = blockIdx.y;
    __shared__ float w[16];
    if (threadIdx.x < 16) w[threadIdx.x] = W1[k * 16 + threadIdx.x];
    __syncthreads();
    int m = blockIdx.x * blockDim.x + threadIdx.x;
    if (m >= M) return;
    size_t e = (size_t)k * M + m;
    float xv = x[in_idx[e]];
    float* r = hacc + (size_t)out_idx[e] * 16;
#pragma unroll
    for (int c = 0; c < 16; ++c) unsafeAtomicAdd(&r[c], xv * w[c]);
}

// In-place BN+ELU over a [*, C] buffer, C = cmask+1 (power of 2)
__global__ void bn_elu_c(float* __restrict__ buf,
                         const float* __restrict__ g, const float* __restrict__ b,
                         const float* __restrict__ m, const float* __restrict__ v,
                         size_t total, int cmask) {
    size_t i = (size_t)blockIdx.x * blockDim.x + threadIdx.x;
    if (i >= total) return;
    int c = (int)(i & (size_t)cmask);
    float scale = g[c] * rsqrtf(v[c] + EPSBN);
    buf[i] = elu1((buf[i] - m[c]) * scale + b[c]);
}

// ---------- Stage 2: gather h row, 16x32 mat-vec vs LDS W2[k], 32 atomics ----------
__global__ void s2_scatter(const float* __restrict__ h,
                           const float* __restrict__ W2,
                           const int* __restrict__ in_idx,
                           const int* __restrict__ out_idx,
                           float* __restrict__ acc, int M) {
    __shared__ float w[16 * 32];
    int k = blockIdx.y;
    for (int t = threadIdx.x; t < 512; t += blockDim.x) w[t] = W2[(size_t)k * 512 + t];
    __syncthreads();
    int m = blockIdx.x * blockDim.x + threadIdx.x;
    if (m >= M) return;
    size_t e = (size_t)k * M + m;
    int in = in_idx[e];
    int out = out_idx[e];
    const float4* hr = (const float4*)(h + (size_t)in * 16);
    float4 h0 = hr[0], h1 = hr[1], h2 = hr[2], h3 = hr[3];
    float hrow[16] = {h0.x, h0.y, h0.z, h0.w, h1.x, h1.y, h1.z, h1.w,
                      h2.x, h2.y, h2.z, h2.w, h3.x, h3.y, h3.z, h3.w};
    float y[32];
#pragma unroll
    for (int d = 0; d < 32; ++d) y[d] = 0.f;
#pragma unroll
    for (int c = 0; c < 16; ++c) {
        float hv = hrow[c];
#pragma unroll
        for (int d = 0; d < 32; ++d) y[d] = fmaf(hv, w[c * 32 + d], y[d]);
    }
    float* ar = acc + (size_t)out * 32;
#pragma unroll
    for (int d = 0; d < 32; ++d) unsafeAtomicAdd(&ar[d], y[d]);
}

extern "C" void kernel_launch(void* const* d_in, const int* in_sizes, int n_in,
                              void* d_out, int out_size, void* d_ws, size_t ws_size,
                              hipStream_t stream) {
    const float* x  = (const float*)d_in[0];
    const float* W1 = (const float*)d_in[1];
    const float* g1 = (const float*)d_in[2];
    const float* b1 = (const float*)d_in[3];
    const float* m1 = (const float*)d_in[4];
    const float* v1 = (const float*)d_in[5];
    const float* W2 = (const float*)d_in[6];
    const float* g2 = (const float*)d_in[7];
    const float* b2 = (const float*)d_in[8];
    const float* m2 = (const float*)d_in[9];
    const float* v2 = (const float*)d_in[10];
    const int* in_idx  = (const int*)d_in[11];
    const int* out_idx = (const int*)d_in[12];

    const int N  = in_sizes[0];           // 400000 (x is [N,1])
    const int C1 = in_sizes[2];           // 16
    const int C2 = in_sizes[7];           // 32
    const int K  = in_sizes[1] / C1;      // 27
    const int M  = in_sizes[11] / K;      // 200000

    float* out = (float*)d_out;

    size_t sBytes = ((size_t)K * N * sizeof(float) + 255) & ~(size_t)255;
    size_t hBytes = (size_t)N * C1 * sizeof(float);

    dim3 blk(256);
    dim3 grdKM((M + 255) / 256, K);

    float* h;
    if (ws_size >= sBytes + hBytes) {
        float* s = (float*)d_ws;
        h = (float*)((char*)d_ws + sBytes);
        hipMemsetAsync(s, 0, (size_t)K * N * sizeof(float), stream);
        s1_scatter_slab<<<grdKM, blk, 0, stream>>>(x, in_idx, out_idx, s, M, N);
        s1_combine<<<dim3((N + 255) / 256), blk, 0, stream>>>(s, W1, g1, b1, m1, v1, h, N, K);
    } else {
        h = (float*)d_ws;
        hipMemsetAsync(h, 0, hBytes, stream);
        s1_scatter_direct<<<grdKM, blk, 0, stream>>>(x, W1, in_idx, out_idx, h, M);
        size_t tot1 = (size_t)N * C1;
        bn_elu_c<<<dim3((unsigned)((tot1 + 255) / 256)), blk, 0, stream>>>(h, g1, b1, m1, v1, tot1, C1 - 1);
    }

    hipMemsetAsync(out, 0, (size_t)N * C2 * sizeof(float), stream);
    s2_scatter<<<grdKM, blk, 0, stream>>>(h, W2, in_idx, out_idx, out, M);
    size_t tot2 = (size_t)N * C2;
    bn_elu_c<<<dim3((unsigned)((tot2 + 255) / 256)), blk, 0, stream>>>(out, g2, b2, m2, v2, tot2, C2 - 1);
}

// Round 2
// 1504.872 us; speedup vs baseline: 6.2282x; 6.2282x over previous
//
#include <hip/hip_runtime.h>
#include <math.h>

#define EPSBN 1e-5f

__device__ __forceinline__ float elu1(float x) { return x > 0.f ? x : expm1f(x); }

// ============================================================================
// CSR build: sort 5.4M (k,m) entries by out_idx via counting sort
// ============================================================================

__global__ void hist_kernel(const int* __restrict__ out_idx, int* __restrict__ cnt, int M) {
    int m = blockIdx.x * blockDim.x + threadIdx.x;
    if (m >= M) return;
    size_t e = (size_t)blockIdx.y * M + m;
    atomicAdd(&cnt[out_idx[e]], 1);
}

__global__ void scan_block_sums(const int* __restrict__ cnt, int* __restrict__ bsum, int N) {
    __shared__ int tmp[256];
    int i = blockIdx.x * 256 + threadIdx.x;
    tmp[threadIdx.x] = (i < N) ? cnt[i] : 0;
    __syncthreads();
    for (int off = 128; off > 0; off >>= 1) {
        if (threadIdx.x < off) tmp[threadIdx.x] += tmp[threadIdx.x + off];
        __syncthreads();
    }
    if (threadIdx.x == 0) bsum[blockIdx.x] = tmp[0];
}

// single block: exclusive scan over nb block sums (in place)
__global__ void scan_bsums(int* __restrict__ bsum, int nb, int* __restrict__ offsets, int N, int E) {
    __shared__ int tmp[256];
    int carry = 0;
    for (int base = 0; base < nb; base += 256) {
        int i = base + threadIdx.x;
        int v = (i < nb) ? bsum[i] : 0;
        tmp[threadIdx.x] = v;
        __syncthreads();
        for (int off = 1; off < 256; off <<= 1) {
            int t = (threadIdx.x >= off) ? tmp[threadIdx.x - off] : 0;
            __syncthreads();
            tmp[threadIdx.x] += t;
            __syncthreads();
        }
        int incl = tmp[threadIdx.x];
        int total = tmp[255];
        if (i < nb) bsum[i] = incl - v + carry;   // exclusive
        carry += total;
        __syncthreads();
    }
    if (threadIdx.x == 0) offsets[N] = E;
}

__global__ void scan_final(const int* __restrict__ cnt, const int* __restrict__ bsum,
                           int* __restrict__ offsets, int* __restrict__ cursor, int N) {
    __shared__ int tmp[256];
    int i = blockIdx.x * 256 + threadIdx.x;
    int v = (i < N) ? cnt[i] : 0;
    tmp[threadIdx.x] = v;
    __syncthreads();
    for (int off = 1; off < 256; off <<= 1) {
        int t = (threadIdx.x >= off) ? tmp[threadIdx.x - off] : 0;
        __syncthreads();
        tmp[threadIdx.x] += t;
        __syncthreads();
    }
    if (i < N) {
        int o = tmp[threadIdx.x] - v + bsum[blockIdx.x];
        offsets[i] = o;
        cursor[i] = o;
    }
}

// entries[pos] = packed (k << 24) | in_idx  (in_idx < 2^24, k < 256)
__global__ void scatter_entries(const int* __restrict__ in_idx, const int* __restrict__ out_idx,
                                int* __restrict__ cursor, unsigned* __restrict__ entries, int M) {
    int m = blockIdx.x * blockDim.x + threadIdx.x;
    if (m >= M) return;
    int k = blockIdx.y;
    size_t e = (size_t)k * M + m;
    int pos = atomicAdd(&cursor[out_idx[e]], 1);
    entries[pos] = (unsigned)in_idx[e] | ((unsigned)k << 24);
}

// ============================================================================
// Gather-style convs (atomic-free), BN+ELU fused
// ============================================================================

// 16 threads per output row (one per channel); block 256 = 16 rows
__global__ void s1_gather(const float* __restrict__ x, const float* __restrict__ W1,
                          const float* __restrict__ g1, const float* __restrict__ b1,
                          const float* __restrict__ m1, const float* __restrict__ v1,
                          const int* __restrict__ offsets, const unsigned* __restrict__ entries,
                          float* __restrict__ h, int N) {
    int row = blockIdx.x * 16 + (threadIdx.x >> 4);
    int c = threadIdx.x & 15;
    if (row >= N) return;
    float scale = g1[c] * rsqrtf(v1[c] + EPSBN);
    float bias = b1[c] - m1[c] * scale;
    int beg = offsets[row], end = offsets[row + 1];
    float acc = 0.f;
    for (int p = beg; p < end; ++p) {
        unsigned pk = entries[p];
        float xv = x[pk & 0xFFFFFFu];              // broadcast within group
        acc = fmaf(xv, W1[(pk >> 24) * 16 + c], acc);
    }
    h[(size_t)row * 16 + c] = elu1(acc * scale + bias);
}

// 32 threads per output row (one per channel); block 256 = 8 rows
__global__ void s2_gather(const float* __restrict__ h, const float* __restrict__ W2,
                          const float* __restrict__ g2, const float* __restrict__ b2,
                          const float* __restrict__ m2, const float* __restrict__ v2,
                          const int* __restrict__ offsets, const unsigned* __restrict__ entries,
                          float* __restrict__ out, int N) {
    int row = blockIdx.x * 8 + (threadIdx.x >> 5);
    int d = threadIdx.x & 31;
    if (row >= N) return;
    float scale = g2[d] * rsqrtf(v2[d] + EPSBN);
    float bias = b2[d] - m2[d] * scale;
    int beg = offsets[row], end = offsets[row + 1];
    float acc = 0.f;
    for (int p = beg; p < end; ++p) {
        unsigned pk = entries[p];
        const float4* hr = (const float4*)(h + (size_t)(pk & 0xFFFFFFu) * 16);
        const float* wr = W2 + (size_t)(pk >> 24) * 512 + d;   // coalesced over d
        float4 h0 = hr[0], h1 = hr[1], h2 = hr[2], h3 = hr[3];
        acc = fmaf(h0.x, wr[0 * 32], acc);
        acc = fmaf(h0.y, wr[1 * 32], acc);
        acc = fmaf(h0.z, wr[2 * 32], acc);
        acc = fmaf(h0.w, wr[3 * 32], acc);
        acc = fmaf(h1.x, wr[4 * 32], acc);
        acc = fmaf(h1.y, wr[5 * 32], acc);
        acc = fmaf(h1.z, wr[6 * 32], acc);
        acc = fmaf(h1.w, wr[7 * 32], acc);
        acc = fmaf(h2.x, wr[8 * 32], acc);
        acc = fmaf(h2.y, wr[9 * 32], acc);
        acc = fmaf(h2.z, wr[10 * 32], acc);
        acc = fmaf(h2.w, wr[11 * 32], acc);
        acc = fmaf(h3.x, wr[12 * 32], acc);
        acc = fmaf(h3.y, wr[13 * 32], acc);
        acc = fmaf(h3.z, wr[14 * 32], acc);
        acc = fmaf(h3.w, wr[15 * 32], acc);
    }
    out[(size_t)row * 32 + d] = elu1(acc * scale + bias);
}

// ============================================================================
// Round-1 fallback kernels (used only if workspace is too small for CSR)
// ============================================================================

__global__ void s1_scatter_slab(const float* __restrict__ x, const int* __restrict__ in_idx,
                                const int* __restrict__ out_idx, float* __restrict__ s, int M, int N) {
    int m = blockIdx.x * blockDim.x + threadIdx.x;
    if (m >= M) return;
    int k = blockIdx.y;
    size_t e = (size_t)k * M + m;
    unsafeAtomicAdd(&s[(size_t)k * N + out_idx[e]], x[in_idx[e]]);
}

__global__ void s1_combine(const float* __restrict__ s, const float* __restrict__ W1,
                           const float* __restrict__ g1, const float* __restrict__ b1,
                           const float* __restrict__ m1, const float* __restrict__ v1,
                           float* __restrict__ h, int N, int K) {
    __shared__ float w[32 * 16];
    __shared__ float sc[16], bi[16];
    for (int t = threadIdx.x; t < K * 16; t += blockDim.x) w[t] = W1[t];
    if (threadIdx.x < 16) {
        float scale = g1[threadIdx.x] * rsqrtf(v1[threadIdx.x] + EPSBN);
        sc[threadIdx.x] = scale;
        bi[threadIdx.x] = b1[threadIdx.x] - m1[threadIdx.x] * scale;
    }
    __syncthreads();
    int n = blockIdx.x * blockDim.x + threadIdx.x;
    if (n >= N) return;
    float acc[16];
#pragma unroll
    for (int c = 0; c < 16; ++c) acc[c] = 0.f;
    for (int k = 0; k < K; ++k) {
        float sv = s[(size_t)k * N + n];
#pragma unroll
        for (int c = 0; c < 16; ++c) acc[c] = fmaf(sv, w[k * 16 + c], acc[c]);
    }
    float4* hv = (float4*)(h + (size_t)n * 16);
#pragma unroll
    for (int q = 0; q < 4; ++q) {
        float4 o;
        o.x = elu1(acc[q * 4 + 0] * sc[q * 4 + 0] + bi[q * 4 + 0]);
        o.y = elu1(acc[q * 4 + 1] * sc[q * 4 + 1] + bi[q * 4 + 1]);
        o.z = elu1(acc[q * 4 + 2] * sc[q * 4 + 2] + bi[q * 4 + 2]);
        o.w = elu1(acc[q * 4 + 3] * sc[q * 4 + 3] + bi[q * 4 + 3]);
        hv[q] = o;
    }
}

__global__ void bn_elu_c(float* __restrict__ buf, const float* __restrict__ g,
                         const float* __restrict__ b, const float* __restrict__ m,
                         const float* __restrict__ v, size_t total, int cmask) {
    size_t i = (size_t)blockIdx.x * blockDim.x + threadIdx.x;
    if (i >= total) return;
    int c = (int)(i & (size_t)cmask);
    float scale = g[c] * rsqrtf(v[c] + EPSBN);
    buf[i] = elu1((buf[i] - m[c]) * scale + b[c]);
}

__global__ void s2_scatter(const float* __restrict__ h, const float* __restrict__ W2,
                           const int* __restrict__ in_idx, const int* __restrict__ out_idx,
                           float* __restrict__ acc, int M) {
    __shared__ float w[16 * 32];
    int k = blockIdx.y;
    for (int t = threadIdx.x; t < 512; t += blockDim.x) w[t] = W2[(size_t)k * 512 + t];
    __syncthreads();
    int m = blockIdx.x * blockDim.x + threadIdx.x;
    if (m >= M) return;
    size_t e = (size_t)k * M + m;
    int in = in_idx[e], out = out_idx[e];
    const float4* hr = (const float4*)(h + (size_t)in * 16);
    float4 h0 = hr[0], h1 = hr[1], h2 = hr[2], h3 = hr[3];
    float hrow[16] = {h0.x, h0.y, h0.z, h0.w, h1.x, h1.y, h1.z, h1.w,
                      h2.x, h2.y, h2.z, h2.w, h3.x, h3.y, h3.z, h3.w};
    float y[32];
#pragma unroll
    for (int d = 0; d < 32; ++d) y[d] = 0.f;
#pragma unroll
    for (int c = 0; c < 16; ++c) {
        float hv = hrow[c];
#pragma unroll
        for (int d = 0; d < 32; ++d) y[d] = fmaf(hv, w[c * 32 + d], y[d]);
    }
    float* ar = acc + (size_t)out * 32;
#pragma unroll
    for (int d = 0; d < 32; ++d) unsafeAtomicAdd(&ar[d], y[d]);
}

// ============================================================================

extern "C" void kernel_launch(void* const* d_in, const int* in_sizes, int n_in,
                              void* d_out, int out_size, void* d_ws, size_t ws_size,
                              hipStream_t stream) {
    const float* x  = (const float*)d_in[0];
    const float* W1 = (const float*)d_in[1];
    const float* g1 = (const float*)d_in[2];
    const float* b1 = (const float*)d_in[3];
    const float* m1 = (const float*)d_in[4];
    const float* v1 = (const float*)d_in[5];
    const float* W2 = (const float*)d_in[6];
    const float* g2 = (const float*)d_in[7];
    const float* b2 = (const float*)d_in[8];
    const float* m2 = (const float*)d_in[9];
    const float* v2 = (const float*)d_in[10];
    const int* in_idx  = (const int*)d_in[11];
    const int* out_idx = (const int*)d_in[12];

    const int N  = in_sizes[0];
    const int C1 = in_sizes[2];           // 16
    const int K  = in_sizes[1] / C1;      // 27
    const int M  = in_sizes[11] / K;      // 200000
    const int E  = K * M;                 // 5.4M
    const int nb = (N + 255) / 256;

    float* out = (float*)d_out;
    dim3 blk(256);
    dim3 grdKM((M + 255) / 256, K);

    // CSR workspace layout (all 4B elements, 256B-aligned sections)
    auto align256 = [](size_t v) { return (v + 255) & ~(size_t)255; };
    size_t cntB   = align256((size_t)N * 4);
    size_t offB   = align256((size_t)(N + 1) * 4);
    size_t curB   = align256((size_t)N * 4);
    size_t bsumB  = align256((size_t)nb * 4);
    size_t entB   = align256((size_t)E * 4);
    size_t hB     = align256((size_t)N * 16 * 4);
    size_t csrNeed = cntB + offB + curB + bsumB + entB + hB;

    if (ws_size >= csrNeed && N < (1 << 24) && K < 256) {
        char* p = (char*)d_ws;
        int* cnt        = (int*)p;            p += cntB;
        int* offsets    = (int*)p;            p += offB;
        int* cursor     = (int*)p;            p += curB;
        int* bsum       = (int*)p;            p += bsumB;
        unsigned* ent   = (unsigned*)p;       p += entB;
        float* h        = (float*)p;

        hipMemsetAsync(cnt, 0, (size_t)N * 4, stream);
        hist_kernel<<<grdKM, blk, 0, stream>>>(out_idx, cnt, M);
        scan_block_sums<<<dim3(nb), blk, 0, stream>>>(cnt, bsum, N);
        scan_bsums<<<dim3(1), blk, 0, stream>>>(bsum, nb, offsets, N, E);
        scan_final<<<dim3(nb), blk, 0, stream>>>(cnt, bsum, offsets, cursor, N);
        scatter_entries<<<grdKM, blk, 0, stream>>>(in_idx, out_idx, cursor, ent, M);
        s1_gather<<<dim3((N + 15) / 16), blk, 0, stream>>>(x, W1, g1, b1, m1, v1, offsets, ent, h, N);
        s2_gather<<<dim3((N + 7) / 8), blk, 0, stream>>>(h, W2, g2, b2, m2, v2, offsets, ent, out, N);
        return;
    }

    // ---------------- fallback: round-1 atomic path ----------------
    size_t sBytes = align256((size_t)K * N * 4);
    size_t hBytes = (size_t)N * 16 * 4;
    float* h = (float*)d_ws;
    if (ws_size >= sBytes + hBytes) {
        float* s = (float*)d_ws;
        h = (float*)((char*)d_ws + sBytes);
        hipMemsetAsync(s, 0, (size_t)K * N * 4, stream);
        s1_scatter_slab<<<grdKM, blk, 0, stream>>>(x, in_idx, out_idx, s, M, N);
        s1_combine<<<dim3((N + 255) / 256), blk, 0, stream>>>(s, W1, g1, b1, m1, v1, h, N, K);
    }
    hipMemsetAsync(out, 0, (size_t)N * 32 * 4, stream);
    s2_scatter<<<grdKM, blk, 0, stream>>>(h, W2, in_idx, out_idx, out, M);
    size_t tot2 = (size_t)N * 32;
    bn_elu_c<<<dim3((unsigned)((tot2 + 255) / 256)), blk, 0, stream>>>(out, g2, b2, m2, v2, tot2, 31);
}